// Round 1
// baseline (815.519 us; speedup 1.0000x reference)
//
#include <hip/hip_runtime.h>

#define NB   32
#define CIN  256
#define CM   64
#define HWSZ 4096
#define OC   384
#define KTOT 192

// ---------- bf16 helpers (round-to-nearest-even), avoid type/alignment pitfalls ----------
static __device__ __forceinline__ unsigned short f2bf(float v) {
    union { float f; unsigned u; } a; a.f = v;
    unsigned r = a.u + 0x7fffu + ((a.u >> 16) & 1u);
    return (unsigned short)(r >> 16);
}
static __device__ __forceinline__ float bf2f(unsigned short u) {
    union { unsigned u; float f; } a; a.u = ((unsigned)u) << 16;
    return a.f;
}

// ---------- precompute W[k][oc] = sum_j fc_w[oc, i*128+j]*fuse_w[j, c]  (k=i*64+c), and b_total ----------
__global__ void kw_pre(const float* __restrict__ fuse_w, const float* __restrict__ fuse_b,
                       const float* __restrict__ fc_w, const float* __restrict__ fc_b,
                       float* __restrict__ W, float* __restrict__ bt) {
    int k = blockIdx.x;      // 0..192 ; 192 = bias block
    int o = threadIdx.x;     // 0..383
    if (k == KTOT) {
        __shared__ float fb[128];
        if (o < 128) fb[o] = fuse_b[o];
        __syncthreads();
        float s = fc_b[o];
        #pragma unroll 4
        for (int q = 0; q < 384; ++q) s += fc_w[o * 384 + q] * fb[q & 127];
        bt[o] = s;
        return;
    }
    int i = k >> 6, c = k & 63;
    __shared__ float fw[128];
    if (o < 128) fw[o] = fuse_w[o * 64 + c];
    __syncthreads();
    float s = 0.f;
    #pragma unroll 8
    for (int j = 0; j < 128; ++j) s += fc_w[o * 384 + i * 128 + j] * fw[j];
    W[k * OC + o] = s;
}

// ---------- spatial mean of x -> xm[n][cin] ----------
__global__ void k1_mean(const float* __restrict__ x, float* __restrict__ xm) {
    int cin = blockIdx.x, n = blockIdx.y;
    const float* p = x + ((size_t)n * CIN + cin) * HWSZ;
    int t = threadIdx.x;
    float s = 0.f;
    #pragma unroll
    for (int j = 0; j < 4; ++j) {
        float4 v = *(const float4*)(p + j * 1024 + 4 * t);
        s += v.x + v.y + v.z + v.w;
    }
    #pragma unroll
    for (int off = 32; off > 0; off >>= 1) s += __shfl_down(s, off);
    __shared__ float ws[4];
    if ((t & 63) == 0) ws[t >> 6] = s;
    __syncthreads();
    if (t == 0) xm[n * CIN + cin] = (ws[0] + ws[1] + ws[2] + ws[3]) * (1.0f / 4096.0f);
}

// ---------- g = relu(xm @ conv_w^T + conv_b); dynamic kernel taps karr[n][c][43] ----------
__global__ void k2_gk(const float* __restrict__ xm, const float* __restrict__ conv_w,
                      const float* __restrict__ conv_b,
                      const float* ck_w, const float* ck_b, const float* ck2_w, const float* ck2_b,
                      const float* ckd4_w, const float* ckd4_b,
                      const float* kern_w, const float* kern_b,
                      const float* kern2_w, const float* kern2_b,
                      const float* kernd4_w, const float* kernd4_b,
                      float* __restrict__ karr) {
    int n = blockIdx.x;
    int c = threadIdx.x;   // 64 threads
    __shared__ float xs[CIN];
    for (int i = c; i < CIN; i += 64) xs[i] = xm[n * CIN + i];
    __syncthreads();
    float a = conv_b[c];
    #pragma unroll 8
    for (int i = 0; i < CIN; ++i) a += xs[i] * conv_w[c * CIN + i];
    float g = fmaxf(a, 0.f);
    float* kp = karr + ((size_t)n * CM + c) * 43;
    float sw = ck_w[0], sb = ck_b[0];
    #pragma unroll
    for (int i = 0; i < 25; ++i) kp[i] = sw * (g * kern_w[i] + kern_b[i]) + sb;
    sw = ck2_w[0]; sb = ck2_b[0];
    #pragma unroll
    for (int i = 0; i < 9; ++i) kp[25 + i] = sw * (g * kern2_w[i] + kern2_b[i]) + sb;
    sw = ckd4_w[0]; sb = ckd4_b[0];
    #pragma unroll
    for (int i = 0; i < 9; ++i) kp[34 + i] = sw * (g * kernd4_w[i] + kernd4_b[i]) + sb;
}

// ---------- f = relu(conv_w @ x + b), store bf16 [n][64][4096] ----------
// grid (16 ptiles, 32 n), block 256. Tile: 256 pixels x 64 oc. Thread: 2 pix x 32 oc.
__global__ void k3_fconv(const float* __restrict__ x, const float* __restrict__ conv_w,
                         const float* __restrict__ conv_b, unsigned short* __restrict__ f) {
    int pt = blockIdx.x, n = blockIdx.y;
    int p0 = pt * 256;
    int t = threadIdx.x;
    int pp = t & 127;          // pixel pair index
    int ocb = (t >> 7) * 32;   // 0 or 32
    __shared__ float lx[8 * 256];
    __shared__ float lw[8 * 64];
    float acc0[32], acc1[32];
    #pragma unroll
    for (int i = 0; i < 32; ++i) { acc0[i] = 0.f; acc1[i] = 0.f; }
    const float* xn = x + (size_t)n * CIN * HWSZ + p0;
    for (int cc = 0; cc < CIN; cc += 8) {
        __syncthreads();
        #pragma unroll
        for (int i = 0; i < 8; ++i)
            lx[i * 256 + t] = xn[(size_t)(cc + i) * HWSZ + t];
        {   // conv_w chunk [8][64]: thread loads float2 of one row
            int o = t >> 2, ii = (t & 3) * 2;
            float2 v = *(const float2*)(conv_w + o * CIN + cc + ii);
            lw[ii * 64 + o] = v.x;
            lw[(ii + 1) * 64 + o] = v.y;
        }
        __syncthreads();
        #pragma unroll
        for (int i = 0; i < 8; ++i) {
            float xv0 = lx[i * 256 + 2 * pp];
            float xv1 = lx[i * 256 + 2 * pp + 1];
            #pragma unroll
            for (int o = 0; o < 32; ++o) {
                float w = lw[i * 64 + ocb + o];
                acc0[o] += w * xv0;
                acc1[o] += w * xv1;
            }
        }
    }
    unsigned short* fb = f + (size_t)n * CM * HWSZ + p0 + 2 * pp;
    #pragma unroll
    for (int o = 0; o < 32; ++o) {
        float b = conv_b[ocb + o];
        float v0 = fmaxf(acc0[o] + b, 0.f);
        float v1 = fmaxf(acc1[o] + b, 0.f);
        unsigned pack = (unsigned)f2bf(v0) | ((unsigned)f2bf(v1) << 16);
        *(unsigned*)(fb + (size_t)(ocb + o) * HWSZ) = pack;
    }
}

// ---------- depthwise convs (5x5 d1, 3x3 d2, 3x3 d4) -> o bf16 [n][192][4096] ----------
// grid (64 c, 32 n), block 256. Full padded plane (72x72) in LDS.
__global__ void k4_dw(const unsigned short* __restrict__ f, const float* __restrict__ karr,
                      unsigned short* __restrict__ o) {
    int c = blockIdx.x, n = blockIdx.y;
    __shared__ float fp[72 * 72];
    __shared__ float kl[43];
    const unsigned short* fplane = f + ((size_t)n * CM + c) * HWSZ;
    int t = threadIdx.x;
    for (int idx = t; idx < 72 * 72; idx += 256) {
        int r = idx / 72, col = idx - r * 72;
        int gh = r - 4, gw = col - 4;
        float v = 0.f;
        if ((unsigned)gh < 64u && (unsigned)gw < 64u) v = bf2f(fplane[gh * 64 + gw]);
        fp[idx] = v;
    }
    if (t < 43) kl[t] = karr[((size_t)n * CM + c) * 43 + t];
    __syncthreads();
    float k1r[25], k2r[9], k3r[9];
    #pragma unroll
    for (int i = 0; i < 25; ++i) k1r[i] = kl[i];
    #pragma unroll
    for (int i = 0; i < 9; ++i) k2r[i] = kl[25 + i];
    #pragma unroll
    for (int i = 0; i < 9; ++i) k3r[i] = kl[34 + i];
    unsigned short* o1 = o + ((size_t)n * KTOT + c) * HWSZ;
    unsigned short* o2 = o1 + (size_t)64 * HWSZ;
    unsigned short* o3 = o1 + (size_t)128 * HWSZ;
    for (int i = 0; i < 16; ++i) {
        int pix = t + i * 256;
        int h = pix >> 6, w = pix & 63;
        int base = (h + 4) * 72 + (w + 4);
        float s1 = 0.f, s2 = 0.f, s3 = 0.f;
        #pragma unroll
        for (int ky = 0; ky < 5; ++ky)
            #pragma unroll
            for (int kx = 0; kx < 5; ++kx)
                s1 += k1r[ky * 5 + kx] * fp[base + (ky - 2) * 72 + (kx - 2)];
        #pragma unroll
        for (int ky = 0; ky < 3; ++ky)
            #pragma unroll
            for (int kx = 0; kx < 3; ++kx)
                s2 += k2r[ky * 3 + kx] * fp[base + (ky * 2 - 2) * 72 + (kx * 2 - 2)];
        #pragma unroll
        for (int ky = 0; ky < 3; ++ky)
            #pragma unroll
            for (int kx = 0; kx < 3; ++kx)
                s3 += k3r[ky * 3 + kx] * fp[base + (ky * 4 - 4) * 72 + (kx * 4 - 4)];
        o1[pix] = f2bf(s1);
        o2[pix] = f2bf(s2);
        o3[pix] = f2bf(s3);
    }
}

// ---------- out = W @ o + b_total, fp32 out [n][384][4096] ----------
// grid (6 ocg, 16 ptiles, 32 n), block 256. Tile 256 pix x 64 oc. Thread: 2 pix x 32 oc.
__global__ void k5_gemm(const unsigned short* __restrict__ od, const float* __restrict__ W,
                        const float* __restrict__ bt, float* __restrict__ out) {
    int og = blockIdx.x, pt = blockIdx.y, n = blockIdx.z;
    int p0 = pt * 256, ocb0 = og * 64;
    int t = threadIdx.x;
    int pp = t & 127;
    int sub = (t >> 7) * 32;   // 0 or 32
    __shared__ float lx[8 * 256];
    __shared__ float lw[8 * 64];
    float acc0[32], acc1[32];
    #pragma unroll
    for (int i = 0; i < 32; ++i) { acc0[i] = 0.f; acc1[i] = 0.f; }
    const unsigned short* on = od + (size_t)n * KTOT * HWSZ + p0;
    for (int kk = 0; kk < KTOT; kk += 8) {
        __syncthreads();
        {   // stage o chunk as f32, 4B/lane loads
            int t2 = t & 127;
            int half = t >> 7;   // 0/1
            #pragma unroll
            for (int i2 = 0; i2 < 8; i2 += 2) {
                int row = i2 + half;
                unsigned v = *(const unsigned*)(on + (size_t)(kk + row) * HWSZ + 2 * t2);
                lx[row * 256 + 2 * t2]     = bf2f((unsigned short)(v & 0xffffu));
                lx[row * 256 + 2 * t2 + 1] = bf2f((unsigned short)(v >> 16));
            }
        }
        {   // W chunk [8][64], coalesced along oc
            #pragma unroll
            for (int u = 0; u < 2; ++u) {
                int idx = u * 256 + t;
                int i = idx >> 6, oo = idx & 63;
                lw[idx] = W[(size_t)(kk + i) * OC + ocb0 + oo];
            }
        }
        __syncthreads();
        #pragma unroll
        for (int i = 0; i < 8; ++i) {
            float xv0 = lx[i * 256 + 2 * pp];
            float xv1 = lx[i * 256 + 2 * pp + 1];
            #pragma unroll
            for (int oo = 0; oo < 32; ++oo) {
                float w = lw[i * 64 + sub + oo];
                acc0[oo] += w * xv0;
                acc1[oo] += w * xv1;
            }
        }
    }
    #pragma unroll
    for (int oo = 0; oo < 32; ++oo) {
        int oc = ocb0 + sub + oo;
        float b = bt[oc];
        float2 v = { acc0[oo] + b, acc1[oo] + b };
        *(float2*)(out + ((size_t)n * OC + oc) * HWSZ + p0 + 2 * pp) = v;
    }
}

extern "C" void kernel_launch(void* const* d_in, const int* in_sizes, int n_in,
                              void* d_out, int out_size, void* d_ws, size_t ws_size,
                              hipStream_t stream) {
    const float* x       = (const float*)d_in[0];
    const float* conv_w  = (const float*)d_in[1];
    const float* conv_b  = (const float*)d_in[2];
    const float* ck_w    = (const float*)d_in[3];
    const float* ck_b    = (const float*)d_in[4];
    const float* ck2_w   = (const float*)d_in[5];
    const float* ck2_b   = (const float*)d_in[6];
    const float* ckd4_w  = (const float*)d_in[7];
    const float* ckd4_b  = (const float*)d_in[8];
    const float* kern_w  = (const float*)d_in[9];
    const float* kern_b  = (const float*)d_in[10];
    const float* kern2_w = (const float*)d_in[11];
    const float* kern2_b = (const float*)d_in[12];
    const float* kernd4_w= (const float*)d_in[13];
    const float* kernd4_b= (const float*)d_in[14];
    const float* fuse_w  = (const float*)d_in[15];
    const float* fuse_b  = (const float*)d_in[16];
    const float* fc_w    = (const float*)d_in[17];
    const float* fc_b    = (const float*)d_in[18];
    float* out = (float*)d_out;

    char* ws = (char*)d_ws;
    float* xm            = (float*)(ws + 0);          //  8192 f
    float* karr          = (float*)(ws + 32768);      //  88064 f
    float* W             = (float*)(ws + 385024);     //  73728 f
    float* bt            = (float*)(ws + 679936);     //  384 f
    unsigned short* f    = (unsigned short*)(ws + 681472);    // 8.39M bf16
    unsigned short* o    = (unsigned short*)(ws + 17458688);  // 25.17M bf16
    // total ws use: 67,790,336 bytes

    kw_pre<<<dim3(193), dim3(384), 0, stream>>>(fuse_w, fuse_b, fc_w, fc_b, W, bt);
    k1_mean<<<dim3(CIN, NB), dim3(256), 0, stream>>>(x, xm);
    k2_gk<<<dim3(NB), dim3(64), 0, stream>>>(xm, conv_w, conv_b,
        ck_w, ck_b, ck2_w, ck2_b, ckd4_w, ckd4_b,
        kern_w, kern_b, kern2_w, kern2_b, kernd4_w, kernd4_b, karr);
    k3_fconv<<<dim3(16, NB), dim3(256), 0, stream>>>(x, conv_w, conv_b, f);
    k4_dw<<<dim3(CM, NB), dim3(256), 0, stream>>>(f, karr, o);
    k5_gemm<<<dim3(6, 16, NB), dim3(256), 0, stream>>>(o, W, bt, out);
}

// Round 2
// 466.231 us; speedup vs baseline: 1.7492x; 1.7492x over previous
//
#include <hip/hip_runtime.h>

#define NB   32
#define CIN  256
#define CM   64
#define HWSZ 4096
#define OC   384
#define KTOT 192

typedef __attribute__((ext_vector_type(8))) short bf16x8;
typedef __attribute__((ext_vector_type(4))) float f32x4;

static __device__ __forceinline__ unsigned short f2bf(float v) {
    union { float f; unsigned u; } a; a.f = v;
    unsigned r = a.u + 0x7fffu + ((a.u >> 16) & 1u);
    return (unsigned short)(r >> 16);
}
static __device__ __forceinline__ float bf2f(unsigned short u) {
    union { unsigned u; float f; } a; a.u = ((unsigned)u) << 16;
    return a.f;
}

// ---------- precompute Wb bf16 [384 oc][192 k] (k-contig), bt[384], cwb bf16 [64 ch][256 k] ----------
__global__ void kw_pre(const float* __restrict__ fuse_w, const float* __restrict__ fuse_b,
                       const float* __restrict__ fc_w, const float* __restrict__ fc_b,
                       const float* __restrict__ conv_w,
                       unsigned short* __restrict__ Wb, float* __restrict__ bt,
                       unsigned short* __restrict__ cwb) {
    int k = blockIdx.x;      // 0..192 ; 192 = bias block + cwb convert
    int o = threadIdx.x;     // 0..383
    if (k == KTOT) {
        __shared__ float fb[128];
        if (o < 128) fb[o] = fuse_b[o];
        __syncthreads();
        float s = fc_b[o];
        #pragma unroll 4
        for (int q = 0; q < 384; ++q) s += fc_w[o * 384 + q] * fb[q & 127];
        bt[o] = s;
        for (int idx = o; idx < CM * CIN; idx += 384) cwb[idx] = f2bf(conv_w[idx]);
        return;
    }
    int i = k >> 6, c = k & 63;
    __shared__ float fw[128];
    if (o < 128) fw[o] = fuse_w[o * 64 + c];
    __syncthreads();
    float s = 0.f;
    #pragma unroll 8
    for (int j = 0; j < 128; ++j) s += fc_w[o * 384 + i * 128 + j] * fw[j];
    Wb[o * KTOT + k] = f2bf(s);
}

// ---------- spatial mean of x -> xm[n][cin] ----------
__global__ void k1_mean(const float* __restrict__ x, float* __restrict__ xm) {
    int cin = blockIdx.x, n = blockIdx.y;
    const float* p = x + ((size_t)n * CIN + cin) * HWSZ;
    int t = threadIdx.x;
    float s = 0.f;
    #pragma unroll
    for (int j = 0; j < 4; ++j) {
        float4 v = *(const float4*)(p + j * 1024 + 4 * t);
        s += v.x + v.y + v.z + v.w;
    }
    #pragma unroll
    for (int off = 32; off > 0; off >>= 1) s += __shfl_down(s, off);
    __shared__ float ws[4];
    if ((t & 63) == 0) ws[t >> 6] = s;
    __syncthreads();
    if (t == 0) xm[n * CIN + cin] = (ws[0] + ws[1] + ws[2] + ws[3]) * (1.0f / 4096.0f);
}

// ---------- g = relu(xm @ conv_w^T + b); dynamic taps karr_t[n][tap(43)][ch(64)] ----------
__global__ void k2_gk(const float* __restrict__ xm, const float* __restrict__ conv_w,
                      const float* __restrict__ conv_b,
                      const float* ck_w, const float* ck_b, const float* ck2_w, const float* ck2_b,
                      const float* ckd4_w, const float* ckd4_b,
                      const float* kern_w, const float* kern_b,
                      const float* kern2_w, const float* kern2_b,
                      const float* kernd4_w, const float* kernd4_b,
                      float* __restrict__ karr_t) {
    int n = blockIdx.x;
    int c = threadIdx.x;   // 64 threads
    __shared__ float xs[CIN];
    for (int i = c; i < CIN; i += 64) xs[i] = xm[n * CIN + i];
    __syncthreads();
    float a = conv_b[c];
    #pragma unroll 8
    for (int i = 0; i < CIN; ++i) a += xs[i] * conv_w[c * CIN + i];
    float g = fmaxf(a, 0.f);
    float* kp = karr_t + (size_t)n * 43 * CM;
    float sw = ck_w[0], sb = ck_b[0];
    #pragma unroll
    for (int i = 0; i < 25; ++i) kp[i * CM + c] = sw * (g * kern_w[i] + kern_b[i]) + sb;
    sw = ck2_w[0]; sb = ck2_b[0];
    #pragma unroll
    for (int i = 0; i < 9; ++i) kp[(25 + i) * CM + c] = sw * (g * kern2_w[i] + kern2_b[i]) + sb;
    sw = ckd4_w[0]; sb = ckd4_b[0];
    #pragma unroll
    for (int i = 0; i < 9; ++i) kp[(34 + i) * CM + c] = sw * (g * kernd4_w[i] + kernd4_b[i]) + sb;
}

// ---------- k3: f_t[n][pix][64] = relu(conv_w @ x + b), MFMA bf16 ----------
// grid (16 ptiles, 32 n), block 256 (4 waves). Block tile: 256 pix (M) x 64 ch (N), K=256.
__global__ void __launch_bounds__(256) k3_fconv(const float* __restrict__ x,
                                                const unsigned short* __restrict__ cwb,
                                                const float* __restrict__ conv_b,
                                                unsigned short* __restrict__ f_t) {
    __shared__ unsigned short Ab[256 * 40];   // x-tile [pix][32k + 8 pad]
    __shared__ unsigned short Bb[64 * 264];   // cwb [ch][256k + 8 pad]
    int pt = blockIdx.x, n = blockIdx.y;
    int p0 = pt * 256;
    int t = threadIdx.x;
    int lane = t & 63, wv = t >> 6;
    int q = lane >> 4, m16 = lane & 15;

    // stage cwb fully (once)
    #pragma unroll
    for (int i = 0; i < 8; ++i) {
        int id = t + i * 256;
        int row = id >> 5, seg = id & 31;
        bf16x8 v = *(const bf16x8*)(cwb + row * CIN + seg * 8);
        *(bf16x8*)(&Bb[row * 264 + seg * 8]) = v;
    }

    f32x4 acc[4][4];
    #pragma unroll
    for (int mt = 0; mt < 4; ++mt)
        #pragma unroll
        for (int nt = 0; nt < 4; ++nt)
            #pragma unroll
            for (int r = 0; r < 4; ++r) acc[mt][nt][r] = 0.f;

    const float* xn = x + (size_t)n * CIN * HWSZ;

    for (int kc = 0; kc < 8; ++kc) {
        __syncthreads();
        // stage + transpose + convert x chunk: 32 cin x 256 pix
        #pragma unroll
        for (int i = 0; i < 2; ++i) {
            int id = t + i * 256;
            int pg = id & 63, kq = id >> 6;      // pg: 4-pixel group, kq: 4-cin group
            int cin = kc * 32 + kq * 4;
            const float* xp = xn + (size_t)cin * HWSZ + p0 + pg * 4;
            float4 r0 = *(const float4*)(xp);
            float4 r1 = *(const float4*)(xp + HWSZ);
            float4 r2 = *(const float4*)(xp + 2 * HWSZ);
            float4 r3 = *(const float4*)(xp + 3 * HWSZ);
            uint2 w;
            w.x = (unsigned)f2bf(r0.x) | ((unsigned)f2bf(r1.x) << 16);
            w.y = (unsigned)f2bf(r2.x) | ((unsigned)f2bf(r3.x) << 16);
            *(uint2*)(&Ab[(pg * 4 + 0) * 40 + kq * 4]) = w;
            w.x = (unsigned)f2bf(r0.y) | ((unsigned)f2bf(r1.y) << 16);
            w.y = (unsigned)f2bf(r2.y) | ((unsigned)f2bf(r3.y) << 16);
            *(uint2*)(&Ab[(pg * 4 + 1) * 40 + kq * 4]) = w;
            w.x = (unsigned)f2bf(r0.z) | ((unsigned)f2bf(r1.z) << 16);
            w.y = (unsigned)f2bf(r2.z) | ((unsigned)f2bf(r3.z) << 16);
            *(uint2*)(&Ab[(pg * 4 + 2) * 40 + kq * 4]) = w;
            w.x = (unsigned)f2bf(r0.w) | ((unsigned)f2bf(r1.w) << 16);
            w.y = (unsigned)f2bf(r2.w) | ((unsigned)f2bf(r3.w) << 16);
            *(uint2*)(&Ab[(pg * 4 + 3) * 40 + kq * 4]) = w;
        }
        __syncthreads();
        bf16x8 af[4], bfr[4];
        #pragma unroll
        for (int mt = 0; mt < 4; ++mt)
            af[mt] = *(const bf16x8*)(&Ab[(wv * 64 + mt * 16 + m16) * 40 + q * 8]);
        #pragma unroll
        for (int nt = 0; nt < 4; ++nt)
            bfr[nt] = *(const bf16x8*)(&Bb[(nt * 16 + m16) * 264 + kc * 32 + q * 8]);
        #pragma unroll
        for (int mt = 0; mt < 4; ++mt)
            #pragma unroll
            for (int nt = 0; nt < 4; ++nt)
                acc[mt][nt] = __builtin_amdgcn_mfma_f32_16x16x32_bf16(af[mt], bfr[nt], acc[mt][nt], 0, 0, 0);
    }

    // epilogue: bias + relu + store bf16 to f_t[n][pix][ch]
    unsigned short* fo = f_t + (size_t)n * HWSZ * CM;
    #pragma unroll
    for (int nt = 0; nt < 4; ++nt) {
        int ch = nt * 16 + m16;
        float b = conv_b[ch];
        #pragma unroll
        for (int mt = 0; mt < 4; ++mt) {
            int pixb = p0 + wv * 64 + mt * 16 + q * 4;
            #pragma unroll
            for (int r = 0; r < 4; ++r) {
                float v = fmaxf(acc[mt][nt][r] + b, 0.f);
                fo[(size_t)(pixb + r) * CM + ch] = f2bf(v);
            }
        }
    }
}

// ---------- k4: depthwise (5x5 d1, 3x3 d2, 3x3 d4) -> o_t[n][pix][192] bf16 ----------
// grid (32 tiles, 32 n), block 256. Tile = 8 rows x 16 cols; LDS holds halo'd tile x 64 ch.
__global__ void __launch_bounds__(256) k4_dw(const unsigned short* __restrict__ f_t,
                                             const float* __restrict__ karr_t,
                                             unsigned short* __restrict__ o_t) {
    __shared__ unsigned short fl[384 * 72];  // [16 rows * 24 cols][64 ch + 8 pad]
    __shared__ float kt[43 * 66];            // [tap][64 ch + 2 pad]
    int tile = blockIdx.x, n = blockIdx.y;
    int r0 = (tile >> 2) * 8, c0 = (tile & 3) * 16;
    int t = threadIdx.x;

    const unsigned short* fn = f_t + (size_t)n * HWSZ * CM;
    #pragma unroll
    for (int i = 0; i < 12; ++i) {
        int id = t + i * 256;           // 3072 tasks: 384 pix x 8 ch-groups
        int cg = id & 7, pl = id >> 3;
        int lr = pl / 24, lc = pl - lr * 24;
        int gr = r0 + lr - 4, gc = c0 + lc - 4;
        bf16x8 v;
        if ((unsigned)gr < 64u && (unsigned)gc < 64u) {
            v = *(const bf16x8*)(fn + (size_t)(gr * 64 + gc) * CM + cg * 8);
        } else {
            #pragma unroll
            for (int j = 0; j < 8; ++j) v[j] = 0;
        }
        *(bf16x8*)(&fl[pl * 72 + cg * 8]) = v;
    }
    const float* kn = karr_t + (size_t)n * 43 * CM;
    for (int id = t; id < 43 * 64; id += 256) {
        int row = id >> 6, col = id & 63;
        kt[row * 66 + col] = kn[id];
    }
    __syncthreads();

    int cp = t & 31;       // channel pair: channels 2cp, 2cp+1
    int pg = t >> 5;       // 0..7
    unsigned short* on = o_t + (size_t)n * HWSZ * KTOT;
    for (int pass = 0; pass < 16; ++pass) {
        int pli = pg + pass * 8;           // 0..127
        int row = pli >> 4, col = pli & 15;
        int base = ((row + 4) * 24 + (col + 4)) * 72 + cp * 2;
        float s1e = 0.f, s1o = 0.f, s2e = 0.f, s2o = 0.f, s3e = 0.f, s3o = 0.f;
        #pragma unroll
        for (int ky = 0; ky < 5; ++ky)
            #pragma unroll
            for (int kx = 0; kx < 5; ++kx) {
                unsigned fv = *(const unsigned*)(&fl[base + ((ky - 2) * 24 + (kx - 2)) * 72]);
                float2 tp = *(const float2*)(&kt[(ky * 5 + kx) * 66 + cp * 2]);
                s1e = fmaf(tp.x, bf2f((unsigned short)(fv & 0xffffu)), s1e);
                s1o = fmaf(tp.y, bf2f((unsigned short)(fv >> 16)), s1o);
            }
        #pragma unroll
        for (int ky = 0; ky < 3; ++ky)
            #pragma unroll
            for (int kx = 0; kx < 3; ++kx) {
                unsigned fv = *(const unsigned*)(&fl[base + ((ky * 2 - 2) * 24 + (kx * 2 - 2)) * 72]);
                float2 tp = *(const float2*)(&kt[(25 + ky * 3 + kx) * 66 + cp * 2]);
                s2e = fmaf(tp.x, bf2f((unsigned short)(fv & 0xffffu)), s2e);
                s2o = fmaf(tp.y, bf2f((unsigned short)(fv >> 16)), s2o);
            }
        #pragma unroll
        for (int ky = 0; ky < 3; ++ky)
            #pragma unroll
            for (int kx = 0; kx < 3; ++kx) {
                unsigned fv = *(const unsigned*)(&fl[base + ((ky * 4 - 4) * 24 + (kx * 4 - 4)) * 72]);
                float2 tp = *(const float2*)(&kt[(34 + ky * 3 + kx) * 66 + cp * 2]);
                s3e = fmaf(tp.x, bf2f((unsigned short)(fv & 0xffffu)), s3e);
                s3o = fmaf(tp.y, bf2f((unsigned short)(fv >> 16)), s3o);
            }
        size_t ob = (size_t)((r0 + row) * 64 + (c0 + col)) * KTOT;
        *(unsigned*)(on + ob + cp * 2)       = (unsigned)f2bf(s1e) | ((unsigned)f2bf(s1o) << 16);
        *(unsigned*)(on + ob + 64 + cp * 2)  = (unsigned)f2bf(s2e) | ((unsigned)f2bf(s2o) << 16);
        *(unsigned*)(on + ob + 128 + cp * 2) = (unsigned)f2bf(s3e) | ((unsigned)f2bf(s3o) << 16);
    }
}

// ---------- k5: out = Wb @ o_t + bt, MFMA bf16, fp32 out [n][384][4096] ----------
// grid (32 ptiles, 32 n, 3 ocg), block 256 (4 waves). Tile 128 oc x 128 pix, K=192 (3 chunks of 64).
__global__ void __launch_bounds__(256) k5_gemm(const unsigned short* __restrict__ o_t,
                                               const unsigned short* __restrict__ Wb,
                                               const float* __restrict__ bt,
                                               float* __restrict__ out) {
    __shared__ unsigned short Ab[128 * 72];   // Wb tile [oc][64k + 8 pad]
    __shared__ unsigned short Bb[128 * 72];   // o_t tile [pix][64k + 8 pad]
    __shared__ float bts[128];
    int pt = blockIdx.x, n = blockIdx.y, og = blockIdx.z;
    int p0 = pt * 128, ocb = og * 128;
    int t = threadIdx.x;
    int lane = t & 63, wv = t >> 6;
    int wm = wv >> 1, wn = wv & 1;
    int q = lane >> 4, m16 = lane & 15;
    if (t < 128) bts[t] = bt[ocb + t];

    f32x4 acc[4][4];
    #pragma unroll
    for (int mt = 0; mt < 4; ++mt)
        #pragma unroll
        for (int nt = 0; nt < 4; ++nt)
            #pragma unroll
            for (int r = 0; r < 4; ++r) acc[mt][nt][r] = 0.f;

    const unsigned short* on = o_t + (size_t)n * HWSZ * KTOT + (size_t)p0 * KTOT;

    for (int kc = 0; kc < 3; ++kc) {
        int k0 = kc * 64;
        __syncthreads();
        #pragma unroll
        for (int i = 0; i < 4; ++i) {
            int id = t + i * 256;          // 1024 tasks: 128 rows x 8 k-groups
            int cg = id & 7, row = id >> 3;
            bf16x8 va = *(const bf16x8*)(Wb + (size_t)(ocb + row) * KTOT + k0 + cg * 8);
            *(bf16x8*)(&Ab[row * 72 + cg * 8]) = va;
            bf16x8 vb = *(const bf16x8*)(on + (size_t)row * KTOT + k0 + cg * 8);
            *(bf16x8*)(&Bb[row * 72 + cg * 8]) = vb;
        }
        __syncthreads();
        #pragma unroll
        for (int ks = 0; ks < 2; ++ks) {
            bf16x8 af[4], bfr[4];
            #pragma unroll
            for (int mt = 0; mt < 4; ++mt)
                af[mt] = *(const bf16x8*)(&Ab[(wm * 64 + mt * 16 + m16) * 72 + ks * 32 + q * 8]);
            #pragma unroll
            for (int nt = 0; nt < 4; ++nt)
                bfr[nt] = *(const bf16x8*)(&Bb[(wn * 64 + nt * 16 + m16) * 72 + ks * 32 + q * 8]);
            #pragma unroll
            for (int mt = 0; mt < 4; ++mt)
                #pragma unroll
                for (int nt = 0; nt < 4; ++nt)
                    acc[mt][nt] = __builtin_amdgcn_mfma_f32_16x16x32_bf16(af[mt], bfr[nt], acc[mt][nt], 0, 0, 0);
        }
    }

    float* outn = out + (size_t)n * OC * HWSZ;
    #pragma unroll
    for (int mt = 0; mt < 4; ++mt) {
        #pragma unroll
        for (int r = 0; r < 4; ++r) {
            int ocl = wm * 64 + mt * 16 + q * 4 + r;
            float b = bts[ocl];
            float* orow = outn + (size_t)(ocb + ocl) * HWSZ + p0 + wn * 64 + m16;
            #pragma unroll
            for (int nt = 0; nt < 4; ++nt)
                orow[nt * 16] = acc[mt][nt][r] + b;
        }
    }
}

extern "C" void kernel_launch(void* const* d_in, const int* in_sizes, int n_in,
                              void* d_out, int out_size, void* d_ws, size_t ws_size,
                              hipStream_t stream) {
    const float* x       = (const float*)d_in[0];
    const float* conv_w  = (const float*)d_in[1];
    const float* conv_b  = (const float*)d_in[2];
    const float* ck_w    = (const float*)d_in[3];
    const float* ck_b    = (const float*)d_in[4];
    const float* ck2_w   = (const float*)d_in[5];
    const float* ck2_b   = (const float*)d_in[6];
    const float* ckd4_w  = (const float*)d_in[7];
    const float* ckd4_b  = (const float*)d_in[8];
    const float* kern_w  = (const float*)d_in[9];
    const float* kern_b  = (const float*)d_in[10];
    const float* kern2_w = (const float*)d_in[11];
    const float* kern2_b = (const float*)d_in[12];
    const float* kernd4_w= (const float*)d_in[13];
    const float* kernd4_b= (const float*)d_in[14];
    const float* fuse_w  = (const float*)d_in[15];
    const float* fuse_b  = (const float*)d_in[16];
    const float* fc_w    = (const float*)d_in[17];
    const float* fc_b    = (const float*)d_in[18];
    float* out = (float*)d_out;

    char* ws = (char*)d_ws;
    float* xm             = (float*)(ws + 0);          // 32 KB
    float* karr_t         = (float*)(ws + 32768);      // 352,256 B
    float* bt             = (float*)(ws + 385024);     // 1,536 B
    unsigned short* Wb    = (unsigned short*)(ws + 386560);    // 147,456 B
    unsigned short* cwb   = (unsigned short*)(ws + 534016);    // 32,768 B
    unsigned short* f_t   = (unsigned short*)(ws + 566784);    // 16.78 MB
    unsigned short* o_t   = (unsigned short*)(ws + 17344000);  // 50.33 MB -> ends 67,675,648

    kw_pre<<<dim3(193), dim3(384), 0, stream>>>(fuse_w, fuse_b, fc_w, fc_b, conv_w, Wb, bt, cwb);
    k1_mean<<<dim3(CIN, NB), dim3(256), 0, stream>>>(x, xm);
    k2_gk<<<dim3(NB), dim3(64), 0, stream>>>(xm, conv_w, conv_b,
        ck_w, ck_b, ck2_w, ck2_b, ckd4_w, ckd4_b,
        kern_w, kern_b, kern2_w, kern2_b, kernd4_w, kernd4_b, karr_t);
    k3_fconv<<<dim3(16, NB), dim3(256), 0, stream>>>(x, cwb, conv_b, f_t);
    k4_dw<<<dim3(32, NB), dim3(256), 0, stream>>>(f_t, karr_t, o_t);
    k5_gemm<<<dim3(32, NB, 3), dim3(256), 0, stream>>>(o_t, Wb, bt, out);
}

// Round 3
// 434.454 us; speedup vs baseline: 1.8771x; 1.0731x over previous
//
#include <hip/hip_runtime.h>

#define NB   32
#define CIN  256
#define CM   64
#define HWSZ 4096
#define OC   384
#define KTOT 192

typedef __attribute__((ext_vector_type(8))) short bf16x8;
typedef __attribute__((ext_vector_type(4))) float f32x4;

static __device__ __forceinline__ unsigned short f2bf(float v) {
    union { float f; unsigned u; } a; a.f = v;
    unsigned r = a.u + 0x7fffu + ((a.u >> 16) & 1u);
    return (unsigned short)(r >> 16);
}
static __device__ __forceinline__ float bf2f(unsigned short u) {
    union { unsigned u; float f; } a; a.u = ((unsigned)u) << 16;
    return a.f;
}

// ---------- precompute Wb bf16 [384 oc][192 k], bt[384], cwb bf16 [64 ch][256 k], zero xm ----------
__global__ void kw_pre(const float* __restrict__ fuse_w, const float* __restrict__ fuse_b,
                       const float* __restrict__ fc_w, const float* __restrict__ fc_b,
                       const float* __restrict__ conv_w,
                       unsigned short* __restrict__ Wb, float* __restrict__ bt,
                       unsigned short* __restrict__ cwb, float* __restrict__ xm) {
    int k = blockIdx.x;      // 0..192 ; 192 = bias block + cwb convert + xm zero
    int o = threadIdx.x;     // 0..383
    if (k == KTOT) {
        __shared__ float fb[128];
        if (o < 128) fb[o] = fuse_b[o];
        __syncthreads();
        float s = fc_b[o];
        #pragma unroll 4
        for (int q = 0; q < 384; ++q) s += fc_w[o * 384 + q] * fb[q & 127];
        bt[o] = s;
        for (int idx = o; idx < CM * CIN; idx += 384) cwb[idx] = f2bf(conv_w[idx]);
        for (int idx = o; idx < NB * CIN; idx += 384) xm[idx] = 0.f;
        return;
    }
    int i = k >> 6, c = k & 63;
    __shared__ float fw[128];
    if (o < 128) fw[o] = fuse_w[o * 64 + c];
    __syncthreads();
    float s = 0.f;
    #pragma unroll 8
    for (int j = 0; j < 128; ++j) s += fc_w[o * 384 + i * 128 + j] * fw[j];
    Wb[o * KTOT + k] = f2bf(s);
}

// ---------- k3: f_t[n][pix][64] = relu(conv_w @ x + b) via MFMA; also accumulates channel sums ----------
// grid (16 ptiles, 32 n), block 256 (4 waves). Tile: 256 pix (M) x 64 ch (N), K=256.
// LDS store remap (kq=id&7): 2-way banks (free). xm gets atomicAdd partial sums (mean fused; k1 deleted).
__global__ void __launch_bounds__(256) k3_fconv(const float* __restrict__ x,
                                                const unsigned short* __restrict__ cwb,
                                                const float* __restrict__ conv_b,
                                                unsigned short* __restrict__ f_t,
                                                float* __restrict__ xm) {
    __shared__ unsigned short Ab[256 * 40];   // x-tile [pix][32k + 8 pad]
    __shared__ unsigned short Bb[64 * 264];   // cwb [ch][256k + 8 pad]
    int pt = blockIdx.x, n = blockIdx.y;
    int p0 = pt * 256;
    int t = threadIdx.x;
    int lane = t & 63;
    int wv = t >> 6;
    int q = lane >> 4, m16 = lane & 15;

    #pragma unroll
    for (int i = 0; i < 8; ++i) {
        int id = t + i * 256;
        int row = id >> 5, seg = id & 31;
        bf16x8 v = *(const bf16x8*)(cwb + row * CIN + seg * 8);
        *(bf16x8*)(&Bb[row * 264 + seg * 8]) = v;
    }

    f32x4 acc[4][4];
    #pragma unroll
    for (int mt = 0; mt < 4; ++mt)
        #pragma unroll
        for (int nt = 0; nt < 4; ++nt)
            #pragma unroll
            for (int r = 0; r < 4; ++r) acc[mt][nt][r] = 0.f;

    const float* xn = x + (size_t)n * CIN * HWSZ;

    for (int kc = 0; kc < 8; ++kc) {
        __syncthreads();
        #pragma unroll
        for (int i = 0; i < 2; ++i) {
            int id = t + i * 256;
            int kq = id & 7, pg = id >> 3;       // kq: 4-cin group, pg: 4-pixel group
            int cin0 = kc * 32 + kq * 4;
            const float* xp = xn + (size_t)cin0 * HWSZ + p0 + pg * 4;
            float4 r0 = *(const float4*)(xp);
            float4 r1 = *(const float4*)(xp + HWSZ);
            float4 r2 = *(const float4*)(xp + 2 * HWSZ);
            float4 r3 = *(const float4*)(xp + 3 * HWSZ);
            uint2 w;
            w.x = (unsigned)f2bf(r0.x) | ((unsigned)f2bf(r1.x) << 16);
            w.y = (unsigned)f2bf(r2.x) | ((unsigned)f2bf(r3.x) << 16);
            *(uint2*)(&Ab[(pg * 4 + 0) * 40 + kq * 4]) = w;
            w.x = (unsigned)f2bf(r0.y) | ((unsigned)f2bf(r1.y) << 16);
            w.y = (unsigned)f2bf(r2.y) | ((unsigned)f2bf(r3.y) << 16);
            *(uint2*)(&Ab[(pg * 4 + 1) * 40 + kq * 4]) = w;
            w.x = (unsigned)f2bf(r0.z) | ((unsigned)f2bf(r1.z) << 16);
            w.y = (unsigned)f2bf(r2.z) | ((unsigned)f2bf(r3.z) << 16);
            *(uint2*)(&Ab[(pg * 4 + 2) * 40 + kq * 4]) = w;
            w.x = (unsigned)f2bf(r0.w) | ((unsigned)f2bf(r1.w) << 16);
            w.y = (unsigned)f2bf(r2.w) | ((unsigned)f2bf(r3.w) << 16);
            *(uint2*)(&Ab[(pg * 4 + 3) * 40 + kq * 4]) = w;
            // fused mean: per-lane pixel sums for 4 cins, xor-reduce over pg bits, 1 atomic/lane<8
            float s0 = r0.x + r0.y + r0.z + r0.w;
            float s1 = r1.x + r1.y + r1.z + r1.w;
            float s2 = r2.x + r2.y + r2.z + r2.w;
            float s3 = r3.x + r3.y + r3.z + r3.w;
            #pragma unroll
            for (int off = 8; off < 64; off <<= 1) {
                s0 += __shfl_xor(s0, off);
                s1 += __shfl_xor(s1, off);
                s2 += __shfl_xor(s2, off);
                s3 += __shfl_xor(s3, off);
            }
            if (lane < 8) {
                float* xp2 = xm + n * CIN + kc * 32 + lane * 4;
                atomicAdd(xp2 + 0, s0);
                atomicAdd(xp2 + 1, s1);
                atomicAdd(xp2 + 2, s2);
                atomicAdd(xp2 + 3, s3);
            }
        }
        __syncthreads();
        bf16x8 af[4], bfr[4];
        #pragma unroll
        for (int mt = 0; mt < 4; ++mt)
            af[mt] = *(const bf16x8*)(&Ab[(wv * 64 + mt * 16 + m16) * 40 + q * 8]);
        #pragma unroll
        for (int nt = 0; nt < 4; ++nt)
            bfr[nt] = *(const bf16x8*)(&Bb[(nt * 16 + m16) * 264 + kc * 32 + q * 8]);
        #pragma unroll
        for (int mt = 0; mt < 4; ++mt)
            #pragma unroll
            for (int nt = 0; nt < 4; ++nt)
                acc[mt][nt] = __builtin_amdgcn_mfma_f32_16x16x32_bf16(af[mt], bfr[nt], acc[mt][nt], 0, 0, 0);
    }

    unsigned short* fo = f_t + (size_t)n * HWSZ * CM;
    #pragma unroll
    for (int nt = 0; nt < 4; ++nt) {
        int ch = nt * 16 + m16;
        float b = conv_b[ch];
        #pragma unroll
        for (int mt = 0; mt < 4; ++mt) {
            int pixb = p0 + wv * 64 + mt * 16 + q * 4;
            #pragma unroll
            for (int r = 0; r < 4; ++r) {
                float v = fmaxf(acc[mt][nt][r] + b, 0.f);
                fo[(size_t)(pixb + r) * CM + ch] = f2bf(v);
            }
        }
    }
}

// ---------- k2: g = relu(mean @ conv_w^T + b); taps karr_t[n][tap(43)][ch(64)] ----------
__global__ void k2_gk(const float* __restrict__ xm, const float* __restrict__ conv_w,
                      const float* __restrict__ conv_b,
                      const float* ck_w, const float* ck_b, const float* ck2_w, const float* ck2_b,
                      const float* ckd4_w, const float* ckd4_b,
                      const float* kern_w, const float* kern_b,
                      const float* kern2_w, const float* kern2_b,
                      const float* kernd4_w, const float* kernd4_b,
                      float* __restrict__ karr_t) {
    int n = blockIdx.x;
    int c = threadIdx.x;   // 64 threads
    __shared__ float xs[CIN];
    for (int i = c; i < CIN; i += 64) xs[i] = xm[n * CIN + i] * (1.0f / 4096.0f);
    __syncthreads();
    float a = conv_b[c];
    #pragma unroll 8
    for (int i = 0; i < CIN; ++i) a += xs[i] * conv_w[c * CIN + i];
    float g = fmaxf(a, 0.f);
    float* kp = karr_t + (size_t)n * 43 * CM;
    float sw = ck_w[0], sb = ck_b[0];
    #pragma unroll
    for (int i = 0; i < 25; ++i) kp[i * CM + c] = sw * (g * kern_w[i] + kern_b[i]) + sb;
    sw = ck2_w[0]; sb = ck2_b[0];
    #pragma unroll
    for (int i = 0; i < 9; ++i) kp[(25 + i) * CM + c] = sw * (g * kern2_w[i] + kern2_b[i]) + sb;
    sw = ckd4_w[0]; sb = ckd4_b[0];
    #pragma unroll
    for (int i = 0; i < 9; ++i) kp[(34 + i) * CM + c] = sw * (g * kernd4_w[i] + kernd4_b[i]) + sb;
}

// ---------- k45: depthwise (5x5 d1, 3x3 d2, 3x3 d4) -> o tile in LDS -> MFMA GEMM (out = Wb@o + bt) ----------
// grid (32 tiles, 32 n), block 512 (8 waves). Tile = 8 rows x 16 cols of pixels.
// Phase 1: halo'd f tile (fl) -> depthwise -> ot[128 pix][192k] in LDS (o never hits HBM).
// Phase 2: 3 x (stage Wb 128-oc chunk into fl region; 128oc x 128pix MFMA; store out).
__global__ void __launch_bounds__(512, 2) k45_dwgemm(const unsigned short* __restrict__ f_t,
                                                     const float* __restrict__ karr_t,
                                                     const unsigned short* __restrict__ Wb,
                                                     const float* __restrict__ bt,
                                                     float* __restrict__ out) {
    __shared__ unsigned short fl[384 * 72];   // phase1: [16r*24c halo pix][64ch+8pad]; phase2: Wb chunk [128oc][192k+8pad]
    __shared__ unsigned short ot[128 * 200];  // [128 pix][192k + 8 pad]
    __shared__ float bts[128];
    int tile = blockIdx.x, n = blockIdx.y;
    int r0 = (tile >> 2) * 8, c0 = (tile & 3) * 16;
    int t = threadIdx.x;
    int lane = t & 63, wv = t >> 6;

    // --- phase 1: stage f halo ---
    const unsigned short* fn = f_t + (size_t)n * HWSZ * CM;
    #pragma unroll
    for (int i = 0; i < 6; ++i) {
        int id = t + i * 512;           // 3072 tasks: 384 pix x 8 ch-groups
        int cg = id & 7, pl = id >> 3;
        int lr = pl / 24, lc = pl - lr * 24;
        int gr = r0 + lr - 4, gc = c0 + lc - 4;
        bf16x8 v;
        if ((unsigned)gr < 64u && (unsigned)gc < 64u) {
            v = *(const bf16x8*)(fn + (size_t)(gr * 64 + gc) * CM + cg * 8);
        } else {
            #pragma unroll
            for (int j = 0; j < 8; ++j) v[j] = 0;
        }
        *(bf16x8*)(&fl[pl * 72 + cg * 8]) = v;
    }
    // taps to registers (global, L2-hot: 11 KB per n shared by 32 blocks)
    int cp = t & 31;       // channel pair: channels 2cp, 2cp+1
    int pg = t >> 5;       // 0..15
    const float* kn = karr_t + (size_t)n * 43 * CM + cp * 2;
    float2 t1[25], t2[9], t3[9];
    #pragma unroll
    for (int i = 0; i < 25; ++i) t1[i] = *(const float2*)(kn + i * CM);
    #pragma unroll
    for (int i = 0; i < 9; ++i) t2[i] = *(const float2*)(kn + (25 + i) * CM);
    #pragma unroll
    for (int i = 0; i < 9; ++i) t3[i] = *(const float2*)(kn + (34 + i) * CM);
    __syncthreads();

    // --- depthwise into ot ---
    for (int pass = 0; pass < 8; ++pass) {
        int pli = pg + pass * 16;           // 0..127
        int row = pli >> 4, col = pli & 15;
        int base = ((row + 4) * 24 + (col + 4)) * 72 + cp * 2;
        float s1e = 0.f, s1o = 0.f, s2e = 0.f, s2o = 0.f, s3e = 0.f, s3o = 0.f;
        #pragma unroll
        for (int ky = 0; ky < 5; ++ky)
            #pragma unroll
            for (int kx = 0; kx < 5; ++kx) {
                unsigned fv = *(const unsigned*)(&fl[base + ((ky - 2) * 24 + (kx - 2)) * 72]);
                float2 tp = t1[ky * 5 + kx];
                s1e = fmaf(tp.x, bf2f((unsigned short)(fv & 0xffffu)), s1e);
                s1o = fmaf(tp.y, bf2f((unsigned short)(fv >> 16)), s1o);
            }
        #pragma unroll
        for (int ky = 0; ky < 3; ++ky)
            #pragma unroll
            for (int kx = 0; kx < 3; ++kx) {
                unsigned fv = *(const unsigned*)(&fl[base + ((ky * 2 - 2) * 24 + (kx * 2 - 2)) * 72]);
                float2 tp = t2[ky * 3 + kx];
                s2e = fmaf(tp.x, bf2f((unsigned short)(fv & 0xffffu)), s2e);
                s2o = fmaf(tp.y, bf2f((unsigned short)(fv >> 16)), s2o);
            }
        #pragma unroll
        for (int ky = 0; ky < 3; ++ky)
            #pragma unroll
            for (int kx = 0; kx < 3; ++kx) {
                unsigned fv = *(const unsigned*)(&fl[base + ((ky * 4 - 4) * 24 + (kx * 4 - 4)) * 72]);
                float2 tp = t3[ky * 3 + kx];
                s3e = fmaf(tp.x, bf2f((unsigned short)(fv & 0xffffu)), s3e);
                s3o = fmaf(tp.y, bf2f((unsigned short)(fv >> 16)), s3o);
            }
        unsigned short* ob = &ot[pli * 200];
        *(unsigned*)(ob + cp * 2)       = (unsigned)f2bf(s1e) | ((unsigned)f2bf(s1o) << 16);
        *(unsigned*)(ob + 64 + cp * 2)  = (unsigned)f2bf(s2e) | ((unsigned)f2bf(s2o) << 16);
        *(unsigned*)(ob + 128 + cp * 2) = (unsigned)f2bf(s3e) | ((unsigned)f2bf(s3o) << 16);
    }

    // --- phase 2: GEMM 384oc x 128pix, K=192 ---
    unsigned short* wbs = fl;   // reuse (51.2 KB <= 55.3 KB)
    int wrow = t >> 2, wqk = t & 3;
    int wm = wv & 3, wn = wv >> 2;
    int q = lane >> 4, m16 = lane & 15;
    float* outn0 = out + (size_t)n * OC * HWSZ;
    for (int ocg = 0; ocg < 3; ++ocg) {
        __syncthreads();
        if (t < 128) bts[t] = bt[ocg * 128 + t];
        #pragma unroll
        for (int j = 0; j < 6; ++j) {
            bf16x8 v = *(const bf16x8*)(Wb + (size_t)(ocg * 128 + wrow) * KTOT + wqk * 48 + j * 8);
            *(bf16x8*)(&wbs[wrow * 200 + wqk * 48 + j * 8]) = v;
        }
        __syncthreads();
        f32x4 acc[2][4];
        #pragma unroll
        for (int mt = 0; mt < 2; ++mt)
            #pragma unroll
            for (int nt = 0; nt < 4; ++nt)
                #pragma unroll
                for (int r = 0; r < 4; ++r) acc[mt][nt][r] = 0.f;
        #pragma unroll
        for (int ks = 0; ks < 6; ++ks) {
            bf16x8 af[2], bfr[4];
            #pragma unroll
            for (int mt = 0; mt < 2; ++mt)
                af[mt] = *(const bf16x8*)(&wbs[(wm * 32 + mt * 16 + m16) * 200 + ks * 32 + q * 8]);
            #pragma unroll
            for (int nt = 0; nt < 4; ++nt)
                bfr[nt] = *(const bf16x8*)(&ot[(wn * 64 + nt * 16 + m16) * 200 + ks * 32 + q * 8]);
            #pragma unroll
            for (int mt = 0; mt < 2; ++mt)
                #pragma unroll
                for (int nt = 0; nt < 4; ++nt)
                    acc[mt][nt] = __builtin_amdgcn_mfma_f32_16x16x32_bf16(af[mt], bfr[nt], acc[mt][nt], 0, 0, 0);
        }
        float* outn = outn0 + (size_t)(ocg * 128) * HWSZ;
        #pragma unroll
        for (int mt = 0; mt < 2; ++mt) {
            #pragma unroll
            for (int r = 0; r < 4; ++r) {
                int ocl = wm * 32 + mt * 16 + q * 4 + r;
                float b = bts[ocl];
                #pragma unroll
                for (int nt = 0; nt < 4; ++nt) {
                    int pl = wn * 64 + nt * 16 + m16;
                    int pr = pl >> 4, pc = pl & 15;
                    outn[(size_t)ocl * HWSZ + (r0 + pr) * 64 + c0 + pc] = acc[mt][nt][r] + b;
                }
            }
        }
    }
}

extern "C" void kernel_launch(void* const* d_in, const int* in_sizes, int n_in,
                              void* d_out, int out_size, void* d_ws, size_t ws_size,
                              hipStream_t stream) {
    const float* x       = (const float*)d_in[0];
    const float* conv_w  = (const float*)d_in[1];
    const float* conv_b  = (const float*)d_in[2];
    const float* ck_w    = (const float*)d_in[3];
    const float* ck_b    = (const float*)d_in[4];
    const float* ck2_w   = (const float*)d_in[5];
    const float* ck2_b   = (const float*)d_in[6];
    const float* ckd4_w  = (const float*)d_in[7];
    const float* ckd4_b  = (const float*)d_in[8];
    const float* kern_w  = (const float*)d_in[9];
    const float* kern_b  = (const float*)d_in[10];
    const float* kern2_w = (const float*)d_in[11];
    const float* kern2_b = (const float*)d_in[12];
    const float* kernd4_w= (const float*)d_in[13];
    const float* kernd4_b= (const float*)d_in[14];
    const float* fuse_w  = (const float*)d_in[15];
    const float* fuse_b  = (const float*)d_in[16];
    const float* fc_w    = (const float*)d_in[17];
    const float* fc_b    = (const float*)d_in[18];
    float* out = (float*)d_out;

    char* ws = (char*)d_ws;
    float* xm             = (float*)(ws + 0);                  // 32 KB (sums, zeroed by kw_pre)
    float* karr_t         = (float*)(ws + 32768);              // 352,256 B
    float* bt             = (float*)(ws + 385024);             // 1,536 B
    unsigned short* Wb    = (unsigned short*)(ws + 386560);    // 147,456 B
    unsigned short* cwb   = (unsigned short*)(ws + 534016);    // 32,768 B
    unsigned short* f_t   = (unsigned short*)(ws + 566784);    // 16.78 MB -> ends ~17.3 MB

    kw_pre<<<dim3(193), dim3(384), 0, stream>>>(fuse_w, fuse_b, fc_w, fc_b, conv_w, Wb, bt, cwb, xm);
    k3_fconv<<<dim3(16, NB), dim3(256), 0, stream>>>(x, cwb, conv_b, f_t, xm);
    k2_gk<<<dim3(NB), dim3(64), 0, stream>>>(xm, conv_w, conv_b,
        ck_w, ck_b, ck2_w, ck2_b, ckd4_w, ckd4_b,
        kern_w, kern_b, kern2_w, kern2_b, kernd4_w, kernd4_b, karr_t);
    k45_dwgemm<<<dim3(32, NB), dim3(512), 0, stream>>>(f_t, karr_t, Wb, bt, out);
}